// Round 3
// baseline (492.730 us; speedup 1.0000x reference)
//
#include <hip/hip_runtime.h>

#define B_ 4096
#define T_ 512
#define F_ 8
#define H_ 16

typedef _Float16 half4_t __attribute__((ext_vector_type(4)));
typedef float f32x4 __attribute__((ext_vector_type(4)));

__device__ __forceinline__ f32x4 mfma16(half4_t a, half4_t b, f32x4 c) {
    return __builtin_amdgcn_mfma_f32_16x16x16f16(a, b, c, 0, 0, 0);
}

__device__ __forceinline__ float sigm(float v) {
    return __builtin_amdgcn_rcpf(1.0f + __expf(-v));
}
// tanh(x) = 1 - 2/(1+e^{2x}); saturates correctly at +/-inf
__device__ __forceinline__ float tanh_(float v) {
    return 1.0f - 2.0f * __builtin_amdgcn_rcpf(1.0f + __expf(2.0f * v));
}

__device__ __forceinline__ half4_t cvt4(float a, float b, float c, float d) {
    return half4_t{(_Float16)a, (_Float16)b, (_Float16)c, (_Float16)d};
}

// One wave = 16 chains (batch elements). MFMA 16x16x16_f16:
//   A[m][k]: lane holds A[m=lane&15][k=4q+i]   (q = lane>>4)
//   B[k][n]: lane holds B[k=4q+i][n=lane&15]
//   D[r][n]: lane holds D[r=4q+i][n=lane&15]
// cols n = chains, rows = gate rows (i,f,g,o blocks of 16). Lane (q,n) gets
// all 4 gates for units 4q..4q+3 of chain n from the 4 per-gate MFMAs,
// updates c/h locally, packs h to f16 -> exactly the next step's B-fragment.
// The whole recurrence closes in registers: no LDS, no shuffles.
__global__ __launch_bounds__(64, 1) void lstm_ae_mfma(
    const float* __restrict__ x,
    const float* __restrict__ eWih, const float* __restrict__ eWhh,
    const float* __restrict__ ebih, const float* __restrict__ ebhh,
    const float* __restrict__ dWih, const float* __restrict__ dWhh,
    const float* __restrict__ dbih, const float* __restrict__ dbhh,
    const float* __restrict__ oW,   const float* __restrict__ ob,
    float* __restrict__ out)
{
    const int lane = threadIdx.x & 63;
    const int q = lane >> 4;          // k/row quad
    const int n = lane & 15;          // chain within wave; A-fragment row m
    const int chain = blockIdx.x * 16 + n;

    // ---------------- weight fragments ----------------
    half4_t eAhh[4], eAih[4], dAhh[4], dAih[4], oA;
    f32x4 eBias[4], dBias[4];
#pragma unroll
    for (int g = 0; g < 4; ++g) {
        const int row = g * 16 + n;
        {
            const float4 w = *(const float4*)(eWhh + row * 16 + 4 * q);
            eAhh[g] = cvt4(w.x, w.y, w.z, w.w);
        }
        if (q < 2) {   // Wih is [64][8]; k-cols 8..15 are zero padding
            const float4 w = *(const float4*)(eWih + row * 8 + 4 * q);
            eAih[g] = cvt4(w.x, w.y, w.z, w.w);
        } else {
            eAih[g] = cvt4(0.f, 0.f, 0.f, 0.f);
        }
        {
            const float4 w = *(const float4*)(dWhh + row * 16 + 4 * q);
            dAhh[g] = cvt4(w.x, w.y, w.z, w.w);
        }
        {
            const float4 w = *(const float4*)(dWih + row * 16 + 4 * q);
            dAih[g] = cvt4(w.x, w.y, w.z, w.w);
        }
        const int rb = g * 16 + 4 * q;   // C/D row base for this lane
        eBias[g] = f32x4{ebih[rb] + ebhh[rb],     ebih[rb+1] + ebhh[rb+1],
                         ebih[rb+2] + ebhh[rb+2], ebih[rb+3] + ebhh[rb+3]};
        dBias[g] = f32x4{dbih[rb] + dbhh[rb],     dbih[rb+1] + dbhh[rb+1],
                         dbih[rb+2] + dbhh[rb+2], dbih[rb+3] + dbhh[rb+3]};
    }
    if (n < 8) {       // oW is [8][16]; A rows 8..15 zero
        const float4 w = *(const float4*)(oW + n * 16 + 4 * q);
        oA = cvt4(w.x, w.y, w.z, w.w);
    } else {
        oA = cvt4(0.f, 0.f, 0.f, 0.f);
    }
    f32x4 oC = (q < 2) ? f32x4{ob[4*q], ob[4*q+1], ob[4*q+2], ob[4*q+3]}
                       : f32x4{0.f, 0.f, 0.f, 0.f};

    // ---------------- encoder ----------------
    half4_t hB = cvt4(0.f, 0.f, 0.f, 0.f);
    float c0 = 0.f, c1 = 0.f, c2 = 0.f, c3 = 0.f;

    const float* xp = x + (size_t)chain * (T_ * F_) + 4 * q;  // valid for q<2
    float4 xa = make_float4(0.f, 0.f, 0.f, 0.f);
    float4 xn = make_float4(0.f, 0.f, 0.f, 0.f);
    if (q < 2) {
        xa = *(const float4*)(xp);
        xn = *(const float4*)(xp + F_);
    }

    for (int t = 0; t < T_; ++t) {
        const half4_t xB = cvt4(xa.x, xa.y, xa.z, xa.w);  // q>=2 lanes: zeros
        xa = xn;
        if (q < 2 && t + 2 < T_) xn = *(const float4*)(xp + (t + 2) * F_);

        f32x4 di = mfma16(eAih[0], xB, eBias[0]);
        f32x4 df = mfma16(eAih[1], xB, eBias[1]);
        f32x4 dg = mfma16(eAih[2], xB, eBias[2]);
        f32x4 dq = mfma16(eAih[3], xB, eBias[3]);
        di = mfma16(eAhh[0], hB, di);
        df = mfma16(eAhh[1], hB, df);
        dg = mfma16(eAhh[2], hB, dg);
        dq = mfma16(eAhh[3], hB, dq);

        float h0, h1, h2, h3;
        { const float ii = sigm(di[0]), ff = sigm(df[0]), gg = tanh_(dg[0]), oo = sigm(dq[0]);
          c0 = ff * c0 + ii * gg;  h0 = oo * tanh_(c0); }
        { const float ii = sigm(di[1]), ff = sigm(df[1]), gg = tanh_(dg[1]), oo = sigm(dq[1]);
          c1 = ff * c1 + ii * gg;  h1 = oo * tanh_(c1); }
        { const float ii = sigm(di[2]), ff = sigm(df[2]), gg = tanh_(dg[2]), oo = sigm(dq[2]);
          c2 = ff * c2 + ii * gg;  h2 = oo * tanh_(c2); }
        { const float ii = sigm(di[3]), ff = sigm(df[3]), gg = tanh_(dg[3]), oo = sigm(dq[3]);
          c3 = ff * c3 + ii * gg;  h3 = oo * tanh_(c3); }
        hB = cvt4(h0, h1, h2, h3);
    }

    // ---------------- decoder constant input projection ----------------
    f32x4 dCc[4];
#pragma unroll
    for (int g = 0; g < 4; ++g) dCc[g] = mfma16(dAih[g], hB, dBias[g]);

    hB = cvt4(0.f, 0.f, 0.f, 0.f);
    c0 = c1 = c2 = c3 = 0.f;
    float* outp = out + (size_t)chain * (T_ * F_) + 4 * q;  // valid for q<2

    // ---------------- decoder + fused output projection ----------------
    for (int t = 0; t < T_; ++t) {
        f32x4 di = mfma16(dAhh[0], hB, dCc[0]);
        f32x4 df = mfma16(dAhh[1], hB, dCc[1]);
        f32x4 dg = mfma16(dAhh[2], hB, dCc[2]);
        f32x4 dq = mfma16(dAhh[3], hB, dCc[3]);

        float h0, h1, h2, h3;
        { const float ii = sigm(di[0]), ff = sigm(df[0]), gg = tanh_(dg[0]), oo = sigm(dq[0]);
          c0 = ff * c0 + ii * gg;  h0 = oo * tanh_(c0); }
        { const float ii = sigm(di[1]), ff = sigm(df[1]), gg = tanh_(dg[1]), oo = sigm(dq[1]);
          c1 = ff * c1 + ii * gg;  h1 = oo * tanh_(c1); }
        { const float ii = sigm(di[2]), ff = sigm(df[2]), gg = tanh_(dg[2]), oo = sigm(dq[2]);
          c2 = ff * c2 + ii * gg;  h2 = oo * tanh_(c2); }
        { const float ii = sigm(di[3]), ff = sigm(df[3]), gg = tanh_(dg[3]), oo = sigm(dq[3]);
          c3 = ff * c3 + ii * gg;  h3 = oo * tanh_(c3); }
        hB = cvt4(h0, h1, h2, h3);

        const f32x4 ov = mfma16(oA, hB, oC);   // out-proj on the new h
        if (q < 2) {
            *(float4*)(outp + t * F_) = make_float4(ov[0], ov[1], ov[2], ov[3]);
        }
    }
}

extern "C" void kernel_launch(void* const* d_in, const int* in_sizes, int n_in,
                              void* d_out, int out_size, void* d_ws, size_t ws_size,
                              hipStream_t stream) {
    (void)in_sizes; (void)n_in; (void)d_ws; (void)ws_size; (void)out_size;
    lstm_ae_mfma<<<dim3(B_ / 16), dim3(64), 0, stream>>>(
        (const float*)d_in[0],
        (const float*)d_in[1], (const float*)d_in[2],
        (const float*)d_in[3], (const float*)d_in[4],
        (const float*)d_in[5], (const float*)d_in[6],
        (const float*)d_in[7], (const float*)d_in[8],
        (const float*)d_in[9], (const float*)d_in[10],
        (float*)d_out);
}